// Round 7
// baseline (536.638 us; speedup 1.0000x reference)
//
#include <hip/hip_runtime.h>
#include <hip/hip_bf16.h>
#include <stdint.h>

#define NUM_TOKENS 16384
#define DIM        4096
#define NEXP       256
#define MB         32        // tokens per block (grid = 512)
#define NKB        (DIM / 32)
#define NWAVES     4
#define MARGIN     0.025f    // ~8.6 sigma of the bf16 gap error (std ~2.9e-3)
#define CAP        16384     // refinement list capacity

typedef __attribute__((ext_vector_type(4))) float   f32x4;
typedef __attribute__((ext_vector_type(8))) __bf16  bf16x8;

static __device__ __forceinline__ bf16x8 pack8(float4 u, float4 v) {
    union { bf16x8 v8; __hip_bfloat162 h[4]; } r;
    r.h[0] = __float22bfloat162_rn(float2{u.x, u.y});
    r.h[1] = __float22bfloat162_rn(float2{u.z, u.w});
    r.h[2] = __float22bfloat162_rn(float2{v.x, v.y});
    r.h[3] = __float22bfloat162_rn(float2{v.z, v.w});
    return r.v8;
}

// ---------------------------------------------------------------- kernel 1
// Pack weight fp32 directly into MFMA B-fragment order (bf16):
//   P[((kb*16 + g)*64 + lane)*8 + j] = w[g*16 + (lane&15)][kb*32 + (lane>>4)*8 + j]
// so a wave's B-fragment load in the gate kernel is one coalesced dwordx4.
// Also zeroes the refinement counter.
__global__ void pack_weights(const float* __restrict__ w,
                             __hip_bfloat16* __restrict__ P,
                             int* __restrict__ counter) {
    if (blockIdx.x == 0 && threadIdx.x == 0) *counter = 0;
    const int gid  = blockIdx.x * blockDim.x + threadIdx.x;  // 0 .. 128*16*64
    const int kb   = gid >> 10;
    const int rem  = gid & 1023;
    const int g    = rem >> 6;
    const int lane = rem & 63;
    const int e    = g * 16 + (lane & 15);
    const int k    = kb * 32 + (lane >> 4) * 8;
    const float4 u = *(const float4*)(w + (size_t)e * DIM + k);
    const float4 v = *(const float4*)(w + (size_t)e * DIM + k + 4);
    *(bf16x8*)(P + (size_t)gid * 8) = pack8(u, v);
}

// ---------------------------------------------------------------- kernel 2
// Barrier-free fused bf16 GEMM + top-2. Block = 32 tokens x 256 experts;
// 256 thr / 4 waves; wave = 32 tokens x 64 experts (mt=2, nt=4).
// NO LDS in the K-loop: A is loaded per-wave straight from x (L1 shares it
// across the block's waves) and converted in-register; B fragments come from
// the pre-packed P with perfectly coalesced loads. The 128-step K-loop has
// no __syncthreads, so the compiler pipelines loads with fine-grained vmcnt
// instead of draining vmcnt(0) at per-iteration barriers (the R2-R6 plateau).
__global__ __launch_bounds__(256, 4) void gate_main(
    const float* __restrict__ x,
    const __hip_bfloat16* __restrict__ P,
    float* __restrict__ out,           // [0,T) weights, [T,2T) indices (as float)
    int* __restrict__ counter,
    int4* __restrict__ entries)
{
    __shared__ float4 cand[NWAVES][MB];         // 2 KB (epilogue only)

    const int tid  = threadIdx.x;
    const int wv   = tid >> 6;          // wave 0..3 -> experts [wv*64, wv*64+64)
    const int lane = tid & 63;
    const int quad = lane >> 4;
    const int col  = lane & 15;
    const int tok0 = blockIdx.x * MB;

    // A rows for this lane (token = tok0 + mt*16 + col), k-offset quad*8
    const float* xr0 = x + (size_t)(tok0 + col) * DIM + quad * 8;
    const float* xr1 = x + (size_t)(tok0 + 16 + col) * DIM + quad * 8;
    // B fragment base for this lane: P + kb*8192 + (wv*4+nt)*512 + lane*8
    const __hip_bfloat16* Pw = P + (size_t)(wv * 4) * 512 + (size_t)lane * 8;

    f32x4 acc[2][4];
    #pragma unroll
    for (int mt = 0; mt < 2; ++mt)
        #pragma unroll
        for (int nt = 0; nt < 4; ++nt)
            acc[mt][nt] = f32x4{0.f, 0.f, 0.f, 0.f};

    for (int kb = 0; kb < NKB; ++kb) {
        const int koff = kb * 32;
        // ---- A: 2 rows x 32B/lane, direct from global (L1-shared in-block)
        float4 a00 = *(const float4*)(xr0 + koff);
        float4 a01 = *(const float4*)(xr0 + koff + 4);
        float4 a10 = *(const float4*)(xr1 + koff);
        float4 a11 = *(const float4*)(xr1 + koff + 4);
        // ---- B: 4 coalesced fragment loads from packed P (L2-resident)
        bf16x8 bh[4];
        #pragma unroll
        for (int nt = 0; nt < 4; ++nt)
            bh[nt] = *(const bf16x8*)(Pw + (size_t)kb * 8192 + nt * 512);
        // ---- convert A in-register (v_cvt_pk_bf16_f32)
        bf16x8 ah0 = pack8(a00, a01);
        bf16x8 ah1 = pack8(a10, a11);
        // ---- 8 MFMAs
        #pragma unroll
        for (int nt = 0; nt < 4; ++nt) {
            acc[0][nt] = __builtin_amdgcn_mfma_f32_16x16x32_bf16(ah0, bh[nt], acc[0][nt], 0, 0, 0);
            acc[1][nt] = __builtin_amdgcn_mfma_f32_16x16x32_bf16(ah1, bh[nt], acc[1][nt], 0, 0, 0);
        }
    }

    // ---- epilogue: per-wave top-2 over its 64 experts, per token.
    // C/D layout (16x16): col = lane&15 (expert), row = quad*4 + reg (token).
    #pragma unroll
    for (int mt = 0; mt < 2; ++mt) {
        #pragma unroll
        for (int r = 0; r < 4; ++r) {
            float t1s = acc[mt][0][r]; int t1e = wv * 64 + col;
            float t2s = acc[mt][1][r]; int t2e = t1e + 16;
            if (t2s > t1s) { float ts = t1s; int te = t1e; t1s = t2s; t1e = t2e; t2s = ts; t2e = te; }
            #pragma unroll
            for (int nt = 2; nt < 4; ++nt) {
                float s = acc[mt][nt][r]; int e = wv * 64 + nt * 16 + col;
                if (s > t1s)      { t2s = t1s; t2e = t1e; t1s = s; t1e = e; }
                else if (s > t2s) { t2s = s; t2e = e; }
            }
            #pragma unroll
            for (int m = 1; m <= 8; m <<= 1) {
                float o1s = __shfl_xor(t1s, m); int o1e = __shfl_xor(t1e, m);
                float o2s = __shfl_xor(t2s, m); int o2e = __shfl_xor(t2e, m);
                bool o1_top = (o1s > t1s) || (o1s == t1s && o1e < t1e);
                if (o1_top) {
                    bool keep_t1 = (t1s > o2s) || (t1s == o2s && t1e < o2e);
                    t2s = keep_t1 ? t1s : o2s; t2e = keep_t1 ? t1e : o2e;
                    t1s = o1s; t1e = o1e;
                } else {
                    bool o1_2nd = (o1s > t2s) || (o1s == t2s && o1e < t2e);
                    if (o1_2nd) { t2s = o1s; t2e = o1e; }
                }
            }
            if (col == 0) {
                int tok = mt * 16 + quad * 4 + r;
                cand[wv][tok] = make_float4(t1s, __int_as_float(t1e), t2s, __int_as_float(t2e));
            }
        }
    }
    __syncthreads();

    // ---- final merge across waves; write outputs + near-tie flags
    if (tid < MB) {
        float4 c0 = cand[0][tid];
        float t1s = c0.x; int t1e = __float_as_int(c0.y);
        float t2s = c0.z; int t2e = __float_as_int(c0.w);
        #pragma unroll
        for (int wvi = 1; wvi < NWAVES; ++wvi) {
            float4 c = cand[wvi][tid];
            float o1s = c.x; int o1e = __float_as_int(c.y);
            float o2s = c.z; int o2e = __float_as_int(c.w);
            bool o1_top = (o1s > t1s) || (o1s == t1s && o1e < t1e);
            if (o1_top) {
                bool keep_t1 = (t1s > o2s) || (t1s == o2s && t1e < o2e);
                t2s = keep_t1 ? t1s : o2s; t2e = keep_t1 ? t1e : o2e;
                t1s = o1s; t1e = o1e;
            } else {
                bool o1_2nd = (o1s > t2s) || (o1s == t2s && o1e < t2e);
                if (o1_2nd) { t2s = o1s; t2e = o1e; }
            }
        }
        const int gtok = tok0 + tid;
        out[gtok] = 1.0f;                       // STE forward value at argmax
        out[NUM_TOKENS + gtok] = (float)t1e;    // index as float
        if (t1s - t2s < MARGIN) {
            int slot = atomicAdd(counter, 1);
            if (slot < CAP) entries[slot] = make_int4(gtok, t1e, t2e, 0);
        }
    }
}

// ---------------------------------------------------------------- kernel 3
// fp64 re-verification of near-tie tokens (one wave per flagged token).
__global__ void refine(const float* __restrict__ x,
                       const float* __restrict__ w,
                       const int* __restrict__ counter,
                       const int4* __restrict__ entries,
                       float* __restrict__ out) {
    const int gwave  = (blockIdx.x * blockDim.x + threadIdx.x) >> 6;
    const int lane   = threadIdx.x & 63;
    const int nwaves = (gridDim.x * blockDim.x) >> 6;
    int n = *counter; if (n > CAP) n = CAP;
    for (int i = gwave; i < n; i += nwaves) {
        int4 e = entries[i];
        const float* xr = x + (size_t)e.x * DIM;
        const float* w1 = w + (size_t)e.y * DIM;
        const float* w2 = w + (size_t)e.z * DIM;
        double d1 = 0.0, d2 = 0.0;
        for (int k = lane; k < DIM; k += 64) {
            double xv = (double)xr[k];
            d1 += xv * (double)w1[k];
            d2 += xv * (double)w2[k];
        }
        #pragma unroll
        for (int m = 32; m > 0; m >>= 1) {
            d1 += __shfl_xor(d1, m);
            d2 += __shfl_xor(d2, m);
        }
        if (lane == 0) {
            int best = (d1 > d2) ? e.y : ((d2 > d1) ? e.z : (e.y < e.z ? e.y : e.z));
            out[NUM_TOKENS + e.x] = (float)best;
        }
    }
}

// ---------------------------------------------------------------- launcher
extern "C" void kernel_launch(void* const* d_in, const int* in_sizes, int n_in,
                              void* d_out, int out_size, void* d_ws, size_t ws_size,
                              hipStream_t stream) {
    const float* x = (const float*)d_in[0];
    const float* w = (const float*)d_in[1];
    float* out = (float*)d_out;

    char* ws = (char*)d_ws;
    __hip_bfloat16* P = (__hip_bfloat16*)ws;                      // 2 MB packed B
    int*  counter = (int*)(ws + (2u << 20));
    int4* entries = (int4*)(ws + (2u << 20) + 16);                // 256 KB

    pack_weights<<<NKB * 16 * 64 / 256, 256, 0, stream>>>(w, P, counter);
    gate_main<<<NUM_TOKENS / MB, 256, 0, stream>>>(x, P, out, counter, entries);
    refine<<<256, 256, 0, stream>>>(x, w, counter, entries, out);
}

// Round 8
// 455.944 us; speedup vs baseline: 1.1770x; 1.1770x over previous
//
#include <hip/hip_runtime.h>
#include <hip/hip_bf16.h>
#include <stdint.h>

#define NUM_TOKENS 16384
#define DIM        4096
#define NEXP       256
#define MB         64        // tokens per block (grid = 256 -> 1 block/CU)
#define BKP        256       // K per phase (32 barriers total, vs 128 in R2-R6)
#define NPH        (DIM / BKP)
#define NKB        (DIM / 32)
#define APAD       264       // A row stride in LDS elems (+8: conflict-free)
#define NWAVES     8
#define MARGIN     0.025f    // ~8.6 sigma of the bf16 gap error (std ~2.9e-3)
#define CAP        16384     // refinement list capacity

typedef __attribute__((ext_vector_type(4))) float   f32x4;
typedef __attribute__((ext_vector_type(8))) __bf16  bf16x8;

static __device__ __forceinline__ bf16x8 pack8(float4 u, float4 v) {
    union { bf16x8 v8; __hip_bfloat162 h[4]; } r;
    r.h[0] = __float22bfloat162_rn(float2{u.x, u.y});
    r.h[1] = __float22bfloat162_rn(float2{u.z, u.w});
    r.h[2] = __float22bfloat162_rn(float2{v.x, v.y});
    r.h[3] = __float22bfloat162_rn(float2{v.z, v.w});
    return r.v8;
}
static __device__ __forceinline__ ushort4 cvt4(float4 u) {
    union { ushort4 u4; __hip_bfloat162 h[2]; } r;
    r.h[0] = __float22bfloat162_rn(float2{u.x, u.y});
    r.h[1] = __float22bfloat162_rn(float2{u.z, u.w});
    return r.u4;
}

// ---------------------------------------------------------------- kernel 1
// Pack weight fp32 into MFMA B-fragment order (bf16) — layout verified R7:
//   P[((kb*16 + g)*64 + lane)*8 + j] = w[g*16+(lane&15)][kb*32+(lane>>4)*8+j]
__global__ void pack_weights(const float* __restrict__ w,
                             __hip_bfloat16* __restrict__ P,
                             int* __restrict__ counter) {
    if (blockIdx.x == 0 && threadIdx.x == 0) *counter = 0;
    const int gid  = blockIdx.x * blockDim.x + threadIdx.x;
    const int kb   = gid >> 10;
    const int rem  = gid & 1023;
    const int g    = rem >> 6;
    const int lane = rem & 63;
    const int e    = g * 16 + (lane & 15);
    const int k    = kb * 32 + (lane >> 4) * 8;
    const float4 u = *(const float4*)(w + (size_t)e * DIM + k);
    const float4 v = *(const float4*)(w + (size_t)e * DIM + k + 4);
    *(bf16x8*)(P + (size_t)gid * 8) = pack8(u, v);
}

// ---------------------------------------------------------------- kernel 2
// Fused bf16 GEMM + top-2. Block = 64 tokens x 256 experts; 512 thr/8 waves;
// wave = 64 tokens x 32 experts (mt=4, nt=2). A staged via LDS in BKP=256
// phases (only 32 barriers); x prefetched one full phase ahead. B comes
// straight from packed P: 16 independent coalesced dwordx4 per phase issued
// up-front, consumed under fine-grained vmcnt across a barrier-free kk loop.
__global__ __launch_bounds__(512, 2) void gate_main(
    const float* __restrict__ x,
    const __hip_bfloat16* __restrict__ P,
    float* __restrict__ out,           // [0,T) weights, [T,2T) indices (as float)
    int* __restrict__ counter,
    int4* __restrict__ entries)
{
    __shared__ unsigned short lAh[MB][APAD];    // ~33 KB
    __shared__ float4 cand[NWAVES][MB];         // 4 KB

    const int tid  = threadIdx.x;
    const int wv   = tid >> 6;          // wave 0..7 -> experts [wv*32, wv*32+32)
    const int lane = tid & 63;
    const int quad = lane >> 4;
    const int col  = lane & 15;
    const int tok0 = blockIdx.x * MB;

    // x staging: load r covers row (r*8 + wv), 16B at col xcol — each instr
    // reads one full 1 KB row slice contiguously (perfect coalescing).
    const int xcol = (lane) * 4;
    const float* xbase = x + (size_t)tok0 * DIM;

    // B fragment base: P + ((kb*16 + g)*64 + lane)*8, g = wv*2 + nt
    const __hip_bfloat16* Pw = P + ((size_t)(wv * 2) * 64 + lane) * 8;

    f32x4 acc[4][2];
    #pragma unroll
    for (int mt = 0; mt < 4; ++mt)
        #pragma unroll
        for (int nt = 0; nt < 2; ++nt)
            acc[mt][nt] = f32x4{0.f, 0.f, 0.f, 0.f};

    // prologue: phase-0 x into regs
    float4 xv[8];
    #pragma unroll
    for (int r = 0; r < 8; ++r)
        xv[r] = *(const float4*)(xbase + (size_t)(r * 8 + wv) * DIM + xcol);

    for (int p = 0; p < NPH; ++p) {
        const int k0 = p * BKP;

        __syncthreads();    // LDS free (previous phase's reads done)
        #pragma unroll
        for (int r = 0; r < 8; ++r)
            *(ushort4*)&lAh[r * 8 + wv][xcol] = cvt4(xv[r]);
        __syncthreads();    // A tile ready

        // ---- issue ALL of this phase's B loads (16 coalesced dwordx4) ----
        bf16x8 bh[8][2];
        #pragma unroll
        for (int kk = 0; kk < 8; ++kk) {
            const size_t kb16 = (size_t)(p * 8 + kk) * 16;
            bh[kk][0] = *(const bf16x8*)(Pw + (kb16 + 0) * 512);
            bh[kk][1] = *(const bf16x8*)(Pw + (kb16 + 1) * 512);
        }
        // ---- prefetch next phase's x (arrives during ~600cyc of compute) --
        if (p + 1 < NPH) {
            #pragma unroll
            for (int r = 0; r < 8; ++r)
                xv[r] = *(const float4*)(xbase + (size_t)(r * 8 + wv) * DIM + k0 + BKP + xcol);
        }
        // ---- barrier-free compute over the phase ------------------------
        #pragma unroll
        for (int kk = 0; kk < 8; ++kk) {
            bf16x8 ah[4];
            #pragma unroll
            for (int mt = 0; mt < 4; ++mt)
                ah[mt] = *(const bf16x8*)&lAh[mt * 16 + col][kk * 32 + quad * 8];
            #pragma unroll
            for (int mt = 0; mt < 4; ++mt) {
                acc[mt][0] = __builtin_amdgcn_mfma_f32_16x16x32_bf16(ah[mt], bh[kk][0], acc[mt][0], 0, 0, 0);
                acc[mt][1] = __builtin_amdgcn_mfma_f32_16x16x32_bf16(ah[mt], bh[kk][1], acc[mt][1], 0, 0, 0);
            }
        }
    }

    // ---- epilogue: per-wave top-2 over its 32 experts, per token.
    // C/D layout (16x16): col = lane&15 (expert), row = quad*4 + reg (token).
    #pragma unroll
    for (int mt = 0; mt < 4; ++mt) {
        #pragma unroll
        for (int r = 0; r < 4; ++r) {
            float s0 = acc[mt][0][r]; int e0 = wv * 32 + col;
            float s1 = acc[mt][1][r]; int e1 = e0 + 16;
            float t1s, t2s; int t1e, t2e;
            if (s1 > s0) { t1s = s1; t1e = e1; t2s = s0; t2e = e0; }
            else         { t1s = s0; t1e = e0; t2s = s1; t2e = e1; }
            #pragma unroll
            for (int m = 1; m <= 8; m <<= 1) {
                float o1s = __shfl_xor(t1s, m); int o1e = __shfl_xor(t1e, m);
                float o2s = __shfl_xor(t2s, m); int o2e = __shfl_xor(t2e, m);
                bool o1_top = (o1s > t1s) || (o1s == t1s && o1e < t1e);
                if (o1_top) {
                    bool keep_t1 = (t1s > o2s) || (t1s == o2s && t1e < o2e);
                    t2s = keep_t1 ? t1s : o2s; t2e = keep_t1 ? t1e : o2e;
                    t1s = o1s; t1e = o1e;
                } else {
                    bool o1_2nd = (o1s > t2s) || (o1s == t2s && o1e < t2e);
                    if (o1_2nd) { t2s = o1s; t2e = o1e; }
                }
            }
            if (col == 0) {
                int tok = mt * 16 + quad * 4 + r;
                cand[wv][tok] = make_float4(t1s, __int_as_float(t1e), t2s, __int_as_float(t2e));
            }
        }
    }
    __syncthreads();

    // ---- final merge across waves; write outputs + near-tie flags
    if (tid < MB) {
        float4 c0 = cand[0][tid];
        float t1s = c0.x; int t1e = __float_as_int(c0.y);
        float t2s = c0.z; int t2e = __float_as_int(c0.w);
        #pragma unroll
        for (int wvi = 1; wvi < NWAVES; ++wvi) {
            float4 c = cand[wvi][tid];
            float o1s = c.x; int o1e = __float_as_int(c.y);
            float o2s = c.z; int o2e = __float_as_int(c.w);
            bool o1_top = (o1s > t1s) || (o1s == t1s && o1e < t1e);
            if (o1_top) {
                bool keep_t1 = (t1s > o2s) || (t1s == o2s && t1e < o2e);
                t2s = keep_t1 ? t1s : o2s; t2e = keep_t1 ? t1e : o2e;
                t1s = o1s; t1e = o1e;
            } else {
                bool o1_2nd = (o1s > t2s) || (o1s == t2s && o1e < t2e);
                if (o1_2nd) { t2s = o1s; t2e = o1e; }
            }
        }
        const int gtok = tok0 + tid;
        out[gtok] = 1.0f;                       // STE forward value at argmax
        out[NUM_TOKENS + gtok] = (float)t1e;    // index as float
        if (t1s - t2s < MARGIN) {
            int slot = atomicAdd(counter, 1);
            if (slot < CAP) entries[slot] = make_int4(gtok, t1e, t2e, 0);
        }
    }
}

// ---------------------------------------------------------------- kernel 3
// fp64 re-verification of near-tie tokens (one wave per flagged token).
__global__ void refine(const float* __restrict__ x,
                       const float* __restrict__ w,
                       const int* __restrict__ counter,
                       const int4* __restrict__ entries,
                       float* __restrict__ out) {
    const int gwave  = (blockIdx.x * blockDim.x + threadIdx.x) >> 6;
    const int lane   = threadIdx.x & 63;
    const int nwaves = (gridDim.x * blockDim.x) >> 6;
    int n = *counter; if (n > CAP) n = CAP;
    for (int i = gwave; i < n; i += nwaves) {
        int4 e = entries[i];
        const float* xr = x + (size_t)e.x * DIM;
        const float* w1 = w + (size_t)e.y * DIM;
        const float* w2 = w + (size_t)e.z * DIM;
        double d1 = 0.0, d2 = 0.0;
        for (int k = lane; k < DIM; k += 64) {
            double xv = (double)xr[k];
            d1 += xv * (double)w1[k];
            d2 += xv * (double)w2[k];
        }
        #pragma unroll
        for (int m = 32; m > 0; m >>= 1) {
            d1 += __shfl_xor(d1, m);
            d2 += __shfl_xor(d2, m);
        }
        if (lane == 0) {
            int best = (d1 > d2) ? e.y : ((d2 > d1) ? e.z : (e.y < e.z ? e.y : e.z));
            out[NUM_TOKENS + e.x] = (float)best;
        }
    }
}

// ---------------------------------------------------------------- launcher
extern "C" void kernel_launch(void* const* d_in, const int* in_sizes, int n_in,
                              void* d_out, int out_size, void* d_ws, size_t ws_size,
                              hipStream_t stream) {
    const float* x = (const float*)d_in[0];
    const float* w = (const float*)d_in[1];
    float* out = (float*)d_out;

    char* ws = (char*)d_ws;
    __hip_bfloat16* P = (__hip_bfloat16*)ws;                      // 2 MB packed B
    int*  counter = (int*)(ws + (2u << 20));
    int4* entries = (int4*)(ws + (2u << 20) + 16);                // 256 KB

    pack_weights<<<NKB * 16 * 64 / 256, 256, 0, stream>>>(w, P, counter);
    gate_main<<<NUM_TOKENS / MB, 512, 0, stream>>>(x, P, out, counter, entries);
    refine<<<256, 256, 0, stream>>>(x, w, counter, entries, out);
}